// Round 1
// baseline (1294.216 us; speedup 1.0000x reference)
//
#include <hip/hip_runtime.h>
#include <math.h>

#define BATCH 16
#define HWDIM 64
#define NPX 4096            // 64*64
#define CDIM 128
#define CC 116              // conv channels
#define KTAPS 1044          // 9*116

__device__ __forceinline__ float swishf(float z) {
    return z / (1.f + __expf(-z));
}

// ---------------- pooled mean of x[..., :12] over H,W ----------------
__global__ void k_pool(const float* __restrict__ x, float* __restrict__ pooled) {
    int b = blockIdx.x;
    int tid = threadIdx.x;
    float s[12];
#pragma unroll
    for (int c = 0; c < 12; ++c) s[c] = 0.f;
    const float* xb = x + (size_t)b * NPX * CDIM;
    for (int px = tid; px < NPX; px += 256) {
        const float4* p = (const float4*)(xb + (size_t)px * CDIM);
        float4 v0 = p[0], v1 = p[1], v2 = p[2];
        s[0] += v0.x; s[1] += v0.y; s[2] += v0.z; s[3] += v0.w;
        s[4] += v1.x; s[5] += v1.y; s[6] += v1.z; s[7] += v1.w;
        s[8] += v2.x; s[9] += v2.y; s[10] += v2.z; s[11] += v2.w;
    }
    __shared__ float red[12][256];
#pragma unroll
    for (int c = 0; c < 12; ++c) red[c][tid] = s[c];
    __syncthreads();
    for (int st = 128; st > 0; st >>= 1) {
        if (tid < st) {
#pragma unroll
            for (int c = 0; c < 12; ++c) red[c][tid] += red[c][tid + st];
        }
        __syncthreads();
    }
    if (tid < 12) pooled[b * 12 + tid] = red[tid][0] * (1.f / 4096.f);
}

// ---------------- 4-qubit circuit ----------------
__device__ void run_circuit(const float* ang, const float* th, float* z) {
    float ar[16], ai[16];
#pragma unroll
    for (int k = 0; k < 16; ++k) { ar[k] = 0.f; ai[k] = 0.f; }
    ar[0] = 1.f;
#pragma unroll
    for (int pass = 0; pass < 2; ++pass) {
        const float* a = pass ? th : ang;
#pragma unroll
        for (int w = 0; w < 4; ++w) {
            float half = 0.5f * a[w];
            float cth = cosf(half), sth = sinf(half);
            int m = 1 << (3 - w);
#pragma unroll
            for (int k = 0; k < 16; ++k) {
                if (k & m) continue;
                int k2 = k | m;
                float r0 = ar[k], i0 = ai[k], r1 = ar[k2], i1 = ai[k2];
                ar[k]  = cth * r0 + sth * i1;
                ai[k]  = cth * i0 - sth * r1;
                ar[k2] = sth * i0 + cth * r1;
                ai[k2] = -sth * r0 + cth * i1;
            }
        }
    }
    // CNOT chain (0,1),(1,2),(2,3),(3,0): swap amp[k],amp[k^mt] when ctrl=1,tgt=0
#pragma unroll
    for (int e = 0; e < 4; ++e) {
        const int cwi[4] = {0, 1, 2, 3};
        const int twi[4] = {1, 2, 3, 0};
        int mc = 1 << (3 - cwi[e]), mt = 1 << (3 - twi[e]);
#pragma unroll
        for (int k = 0; k < 16; ++k) {
            if ((k & mc) && !(k & mt)) {
                int k2 = k | mt;
                float tr = ar[k]; ar[k] = ar[k2]; ar[k2] = tr;
                float ti = ai[k]; ai[k] = ai[k2]; ai[k2] = ti;
            }
        }
    }
    float zz[4] = {0.f, 0.f, 0.f, 0.f};
#pragma unroll
    for (int k = 0; k < 16; ++k) {
        float p = ar[k] * ar[k] + ai[k] * ai[k];
#pragma unroll
        for (int w = 0; w < 4; ++w) zz[w] += ((k >> (3 - w)) & 1) ? -p : p;
    }
#pragma unroll
    for (int w = 0; w < 4; ++w) z[w] = zz[w];
}

__global__ void k_circ1(const float* __restrict__ pooled, const float* __restrict__ qp,
                        float* __restrict__ y1) {
    int tid = threadIdx.x;
    if (tid >= 48) return;
    int b = tid / 3, g = tid % 3;
    float z[4];
    run_circuit(pooled + b * 12 + g * 4, qp + g * 4, z);
#pragma unroll
    for (int w = 0; w < 4; ++w) y1[b * 12 + g * 4 + w] = z[w];
}

__global__ void k_circ2(const float* __restrict__ y1, const float* __restrict__ A,
                        const float* __restrict__ B, const float* __restrict__ qp,
                        float* __restrict__ y2) {
    int tid = threadIdx.x;
    if (tid >= 48) return;
    int b = tid / 3, g = tid % 3;
    float pin[4], z[4];
#pragma unroll
    for (int w = 0; w < 4; ++w) {
        int c = g * 4 + w;
        float v = y1[b * 12 + c];
        pin[w] = swishf(v * A[b * 128 + c] + B[b * 128 + c]);
    }
    run_circuit(pin, qp + g * 4, z);
#pragma unroll
    for (int w = 0; w < 4; ++w) y2[b * 12 + g * 4 + w] = z[w];
}

// ---------------- time MLP: t = swish(te) @ W + b ----------------
__global__ void k_time(const float* __restrict__ te, const float* __restrict__ W,
                       const float* __restrict__ tb, float* __restrict__ t) {
    int b = blockIdx.x, tid = threadIdx.x;
    __shared__ float se[512];
    for (int k = tid; k < 512; k += 256) {
        float z = te[b * 512 + k];
        se[k] = swishf(z);
    }
    __syncthreads();
    float acc = tb[tid];
    for (int k = 0; k < 512; ++k) acc += se[k] * W[k * 256 + tid];
    t[b * 256 + tid] = acc;
}

// ---------------- weight standardization -> padded [tap][i][128] ----------------
__global__ void k_wstd(const float* __restrict__ K, float* __restrict__ kq) {
    int o = blockIdx.x;
    int tid = threadIdx.x;
    if (o >= CC) {
        for (int idx = tid; idx < KTAPS; idx += 256) kq[idx * 128 + o] = 0.f;
        return;
    }
    float s = 0.f, ss = 0.f;
    for (int idx = tid; idx < KTAPS; idx += 256) {
        float v = K[idx * CC + o];
        s += v; ss += v * v;
    }
    __shared__ float rs[256], rss[256];
    __shared__ float mb[2];
    rs[tid] = s; rss[tid] = ss;
    __syncthreads();
    for (int st = 128; st > 0; st >>= 1) {
        if (tid < st) { rs[tid] += rs[tid + st]; rss[tid] += rss[tid + st]; }
        __syncthreads();
    }
    if (tid == 0) {
        float m = rs[0] * (1.f / KTAPS);
        float var = rss[0] * (1.f / KTAPS) - m * m;
        mb[0] = m;
        mb[1] = rsqrtf(var + 1e-5f);
    }
    __syncthreads();
    float m = mb[0], inv = mb[1];
    for (int idx = tid; idx < KTAPS; idx += 256)
        kq[idx * 128 + o] = (K[idx * CC + o] - m) * inv;
}

// ---------------- direct conv: 32 px x 128 oc per block, 4px x 8oc per thread ----------------
__launch_bounds__(128)
__global__ void k_conv(const float* __restrict__ in, int in_stride,
                       const float* __restrict__ kq, const float* __restrict__ bias,
                       float* __restrict__ outp) {
    __shared__ float xs[3 * CC * 36];
    int b = blockIdx.z, h = blockIdx.y, w0 = blockIdx.x * 32;
    int tid = threadIdx.x;
    // stage x tile: rows h-1..h+1, w0-1..w0+32, all 116 in-channels
    for (int idx = tid; idx < 3 * 34 * CC; idx += 128) {
        int r = idx / (34 * CC);
        int rem = idx - r * (34 * CC);
        int tw = rem / CC;
        int i = rem - tw * CC;
        int hi = h + r - 1, wi = w0 + tw - 1;
        float v = 0.f;
        if (hi >= 0 && hi < HWDIM && wi >= 0 && wi < HWDIM)
            v = in[(((size_t)(b * HWDIM + hi)) * HWDIM + wi) * in_stride + i];
        xs[(r * CC + i) * 36 + tw] = v;
    }
    __syncthreads();

    int pxg = tid >> 4, ocg = tid & 15;
    int px0 = pxg * 4, oc0 = ocg * 8;
    float acc[4][8];
#pragma unroll
    for (int j = 0; j < 4; ++j)
#pragma unroll
        for (int o = 0; o < 8; ++o) acc[j][o] = 0.f;

    for (int p = 0; p < 3; ++p) {
        for (int i = 0; i < CC; ++i) {
            const float* xrow = &xs[(p * CC + i) * 36 + px0];
            float xw[8];
            *(float4*)&xw[0] = *(const float4*)xrow;
            *(float4*)&xw[4] = *(const float4*)(xrow + 4);
            const float* kbase = &kq[((p * 3) * CC + i) * 128 + oc0];
#pragma unroll
            for (int q = 0; q < 3; ++q) {
                float kk[8];
                *(float4*)&kk[0] = *(const float4*)(kbase + q * CC * 128);
                *(float4*)&kk[4] = *(const float4*)(kbase + q * CC * 128 + 4);
#pragma unroll
                for (int j = 0; j < 4; ++j) {
                    float xv = xw[q + j];
#pragma unroll
                    for (int o = 0; o < 8; ++o) acc[j][o] += xv * kk[o];
                }
            }
        }
    }
    size_t obase = (((size_t)(b * HWDIM + h)) * HWDIM + w0 + px0) * CC;
#pragma unroll
    for (int j = 0; j < 4; ++j) {
#pragma unroll
        for (int o = 0; o < 8; ++o) {
            int oc = oc0 + o;
            if (oc < CC) outp[obase + (size_t)j * CC + oc] = acc[j][o] + bias[oc];
        }
    }
}

// ---------------- GN stats: per (b,g) mean/inv_std over 4096 px x 16 ch ----------------
__global__ void k_stats(const float* __restrict__ hc, const float* __restrict__ yq,
                        float* __restrict__ stats) {
    int bg = blockIdx.x;
    int b = bg >> 3, g = bg & 7;
    int tid = threadIdx.x;
    int sc = (g == 0) ? 0 : 16 * g - 12;   // hc channel start
    int cnt = (g == 0) ? 4 : 16;           // varying channels in this group
    const float* base = hc + (size_t)b * NPX * CC;
    float s = 0.f, ss = 0.f;
    int total = NPX * cnt;
    for (int idx = tid; idx < total; idx += 256) {
        int px = idx / cnt;
        int c = idx - px * cnt;
        float v = base[(size_t)px * CC + sc + c];
        s += v; ss += v * v;
    }
    __shared__ float rs[256], rss[256];
    rs[tid] = s; rss[tid] = ss;
    __syncthreads();
    for (int st = 128; st > 0; st >>= 1) {
        if (tid < st) { rs[tid] += rs[tid + st]; rss[tid] += rss[tid + st]; }
        __syncthreads();
    }
    if (tid == 0) {
        float S = rs[0], SS = rss[0];
        if (g == 0) {
#pragma unroll
            for (int c = 0; c < 12; ++c) {
                float v = yq[b * 12 + c];
                S += 4096.f * v;
                SS += 4096.f * v * v;
            }
        }
        const float N = 65536.f;
        float mu = S / N;
        float var = SS / N - mu * mu;
        stats[bg * 2] = mu;
        stats[bg * 2 + 1] = rsqrtf(var + 1e-6f);
    }
}

// ---------------- per-(b,c) affine coefficients ----------------
__global__ void k_coef0(const float* __restrict__ stats, const float* __restrict__ gs,
                        const float* __restrict__ gb, const float* __restrict__ t,
                        float* __restrict__ A, float* __restrict__ B) {
    int idx = blockIdx.x * 256 + threadIdx.x;
    if (idx >= 16 * 128) return;
    int b = idx >> 7, c = idx & 127, g = c >> 4;
    float mu = stats[(b * 8 + g) * 2], isd = stats[(b * 8 + g) * 2 + 1];
    float sc = t[b * 256 + c], sh = t[b * 256 + 128 + c];
    float a = isd * gs[c];
    float bb = gb[c] - mu * a;
    A[idx] = a * (1.f + sc);
    B[idx] = bb * (1.f + sc) + sh;
}

__global__ void k_coef1(const float* __restrict__ stats, const float* __restrict__ gs,
                        const float* __restrict__ gb, const float* __restrict__ y2,
                        float* __restrict__ A2, float* __restrict__ B2,
                        float* __restrict__ oq) {
    int idx = blockIdx.x * 256 + threadIdx.x;
    if (idx >= 16 * 128) return;
    int b = idx >> 7, c = idx & 127, g = c >> 4;
    float mu = stats[(b * 8 + g) * 2], isd = stats[(b * 8 + g) * 2 + 1];
    float a = isd * gs[c];
    float bb = gb[c] - mu * a;
    A2[idx] = a;
    B2[idx] = bb;
    if (c < 12) oq[b * 12 + c] = swishf(y2[b * 12 + c] * a + bb);
}

// ---------------- h_act = swish(A*hc + B) on the 116 conv channels ----------------
__global__ void k_hact(const float* __restrict__ hc, const float* __restrict__ A,
                       const float* __restrict__ B, float* __restrict__ ha) {
    int idx = blockIdx.x * 256 + threadIdx.x;
    const int n = BATCH * NPX * 29;
    if (idx >= n) return;
    int px = idx / 29;
    int c4 = idx - px * 29;
    int b = px >> 12;
    int c = 12 + c4 * 4;
    float4 v = *(const float4*)(hc + (size_t)px * CC + c4 * 4);
    float4 a = *(const float4*)(A + b * 128 + c);
    float4 bb = *(const float4*)(B + b * 128 + c);
    float4 r;
    r.x = swishf(v.x * a.x + bb.x);
    r.y = swishf(v.y * a.y + bb.y);
    r.z = swishf(v.z * a.z + bb.z);
    r.w = swishf(v.w * a.w + bb.w);
    *(float4*)(ha + (size_t)px * CC + c4 * 4) = r;
}

// ---------------- out = x + swish(A2*v + B2) ----------------
__global__ void k_final(const float* __restrict__ x, const float* __restrict__ hc2,
                        const float* __restrict__ A2, const float* __restrict__ B2,
                        const float* __restrict__ oq, float* __restrict__ outp) {
    int idx = blockIdx.x * 256 + threadIdx.x;
    const int n = BATCH * NPX * 32;
    if (idx >= n) return;
    int px = idx >> 5;
    int c4 = idx & 31;
    int b = px >> 12;
    int c = c4 * 4;
    float4 xv = *(const float4*)(x + (size_t)px * CDIM + c);
    float4 r;
    if (c4 < 3) {
        const float* q = oq + b * 12 + c;
        r.x = xv.x + q[0]; r.y = xv.y + q[1]; r.z = xv.z + q[2]; r.w = xv.w + q[3];
    } else {
        float4 hv = *(const float4*)(hc2 + (size_t)px * CC + (c - 12));
        float4 a = *(const float4*)(A2 + b * 128 + c);
        float4 bb = *(const float4*)(B2 + b * 128 + c);
        r.x = xv.x + swishf(hv.x * a.x + bb.x);
        r.y = xv.y + swishf(hv.y * a.y + bb.y);
        r.z = xv.z + swishf(hv.z * a.z + bb.z);
        r.w = xv.w + swishf(hv.w * a.w + bb.w);
    }
    *(float4*)(outp + (size_t)px * CDIM + c) = r;
}

extern "C" void kernel_launch(void* const* d_in, const int* in_sizes, int n_in,
                              void* d_out, int out_size, void* d_ws, size_t ws_size,
                              hipStream_t stream) {
    const float* x        = (const float*)d_in[0];
    const float* time_emb = (const float*)d_in[1];
    const float* qparams  = (const float*)d_in[2];
    const float* c0k      = (const float*)d_in[3];
    const float* c0b      = (const float*)d_in[4];
    const float* c1k      = (const float*)d_in[5];
    const float* c1b      = (const float*)d_in[6];
    const float* g0s      = (const float*)d_in[7];
    const float* g0b      = (const float*)d_in[8];
    const float* g1s      = (const float*)d_in[9];
    const float* g1b      = (const float*)d_in[10];
    const float* tw       = (const float*)d_in[11];
    const float* tb       = (const float*)d_in[12];
    float* outp = (float*)d_out;
    float* ws = (float*)d_ws;

    size_t o = 0;
    auto alloc = [&](size_t n) { size_t r = o; o += (n + 15) & ~(size_t)15; return r; };
    float* pooled = ws + alloc(192);
    float* y1     = ws + alloc(192);
    float* y2     = ws + alloc(192);
    float* t      = ws + alloc(4096);
    float* st0    = ws + alloc(256);
    float* st1    = ws + alloc(256);
    float* A      = ws + alloc(2048);
    float* Bc     = ws + alloc(2048);
    float* A2     = ws + alloc(2048);
    float* B2     = ws + alloc(2048);
    float* oq     = ws + alloc(192);
    float* kq0    = ws + alloc((size_t)KTAPS * 128);
    float* kq1    = ws + alloc((size_t)KTAPS * 128);
    float* bufA   = ws + alloc((size_t)BATCH * NPX * CC);  // hc0, then hc2
    float* bufB   = outp;                                  // h_act scratch lives in d_out

    k_pool<<<16, 256, 0, stream>>>(x, pooled);
    k_circ1<<<1, 64, 0, stream>>>(pooled, qparams, y1);
    k_time<<<16, 256, 0, stream>>>(time_emb, tw, tb, t);
    k_wstd<<<128, 256, 0, stream>>>(c0k, kq0);
    k_wstd<<<128, 256, 0, stream>>>(c1k, kq1);

    dim3 cgrid(2, HWDIM, BATCH);
    k_conv<<<cgrid, 128, 0, stream>>>(x + 12, CDIM, kq0, c0b, bufA);
    k_stats<<<128, 256, 0, stream>>>(bufA, y1, st0);
    k_coef0<<<8, 256, 0, stream>>>(st0, g0s, g0b, t, A, Bc);
    k_hact<<<(BATCH * NPX * 29 + 255) / 256, 256, 0, stream>>>(bufA, A, Bc, bufB);
    k_circ2<<<1, 64, 0, stream>>>(y1, A, Bc, qparams, y2);

    k_conv<<<cgrid, 128, 0, stream>>>(bufB, CC, kq1, c1b, bufA);
    k_stats<<<128, 256, 0, stream>>>(bufA, y2, st1);
    k_coef1<<<8, 256, 0, stream>>>(st1, g1s, g1b, y2, A2, B2, oq);
    k_final<<<(BATCH * NPX * 32 + 255) / 256, 256, 0, stream>>>(x, bufA, A2, B2, oq, outp);
}

// Round 2
// 182.240 us; speedup vs baseline: 7.1017x; 7.1017x over previous
//
#include <hip/hip_runtime.h>
#include <math.h>

#define BATCH 16
#define NPX 4096            // 64*64
#define CDIM 128
#define CC 116              // conv channels
#define KTAPS 1044          // 9*116

using u16 = unsigned short;
typedef __attribute__((ext_vector_type(8))) short short8;
typedef __attribute__((ext_vector_type(4))) float f32x4;

__device__ __forceinline__ float swishf(float z) {
    return z / (1.f + __expf(-z));
}
__device__ __forceinline__ float bf2f(u16 u) {
    union { unsigned int i; float f; } v; v.i = ((unsigned int)u) << 16; return v.f;
}
__device__ __forceinline__ u16 f2bf(float f) {
    union { float f; unsigned int i; } v; v.f = f;
    unsigned int r = v.i + 0x7fffu + ((v.i >> 16) & 1u);
    return (u16)(r >> 16);
}

// ---------------- x conv-channels -> bf16 padded activation buffer ----------------
__global__ void k_prep(const float* __restrict__ x, u16* __restrict__ act) {
    int gid = blockIdx.x * 256 + threadIdx.x;
    if (gid >= BATCH * NPX * 4) return;
    int px = gid >> 2, part = gid & 3;
    const float* xp = x + (size_t)px * CDIM + 12 + part * 32;
    u16 tmp[32];
#pragma unroll
    for (int j = 0; j < 8; ++j) {
        int base = part * 32 + j * 4;   // conv channel of first elem; 116%4==0 -> no mixed groups
        if (base <= 112) {
            float4 v = *(const float4*)(xp + j * 4);
            tmp[j * 4 + 0] = f2bf(v.x); tmp[j * 4 + 1] = f2bf(v.y);
            tmp[j * 4 + 2] = f2bf(v.z); tmp[j * 4 + 3] = f2bf(v.w);
        } else {
            tmp[j * 4 + 0] = 0; tmp[j * 4 + 1] = 0; tmp[j * 4 + 2] = 0; tmp[j * 4 + 3] = 0;
        }
    }
    u16* ap = act + (size_t)px * CDIM + part * 32;
#pragma unroll
    for (int j = 0; j < 4; ++j) *(short8*)(ap + j * 8) = *(const short8*)&tmp[j * 8];
}

// ---------------- pooled mean of x[..., :12] over H,W ----------------
__global__ void k_pool(const float* __restrict__ x, float* __restrict__ pooled) {
    int b = blockIdx.x;
    int tid = threadIdx.x;
    float s[12];
#pragma unroll
    for (int c = 0; c < 12; ++c) s[c] = 0.f;
    const float* xb = x + (size_t)b * NPX * CDIM;
    for (int px = tid; px < NPX; px += 256) {
        const float4* p = (const float4*)(xb + (size_t)px * CDIM);
        float4 v0 = p[0], v1 = p[1], v2 = p[2];
        s[0] += v0.x; s[1] += v0.y; s[2] += v0.z; s[3] += v0.w;
        s[4] += v1.x; s[5] += v1.y; s[6] += v1.z; s[7] += v1.w;
        s[8] += v2.x; s[9] += v2.y; s[10] += v2.z; s[11] += v2.w;
    }
    __shared__ float red[12][256];
#pragma unroll
    for (int c = 0; c < 12; ++c) red[c][tid] = s[c];
    __syncthreads();
    for (int st = 128; st > 0; st >>= 1) {
        if (tid < st) {
#pragma unroll
            for (int c = 0; c < 12; ++c) red[c][tid] += red[c][tid + st];
        }
        __syncthreads();
    }
    if (tid < 12) pooled[b * 12 + tid] = red[tid][0] * (1.f / 4096.f);
}

// ---------------- 4-qubit circuit ----------------
__device__ void run_circuit(const float* ang, const float* th, float* z) {
    float ar[16], ai[16];
#pragma unroll
    for (int k = 0; k < 16; ++k) { ar[k] = 0.f; ai[k] = 0.f; }
    ar[0] = 1.f;
#pragma unroll
    for (int pass = 0; pass < 2; ++pass) {
        const float* a = pass ? th : ang;
#pragma unroll
        for (int w = 0; w < 4; ++w) {
            float half = 0.5f * a[w];
            float cth = cosf(half), sth = sinf(half);
            int m = 1 << (3 - w);
#pragma unroll
            for (int k = 0; k < 16; ++k) {
                if (k & m) continue;
                int k2 = k | m;
                float r0 = ar[k], i0 = ai[k], r1 = ar[k2], i1 = ai[k2];
                ar[k]  = cth * r0 + sth * i1;
                ai[k]  = cth * i0 - sth * r1;
                ar[k2] = sth * i0 + cth * r1;
                ai[k2] = -sth * r0 + cth * i1;
            }
        }
    }
#pragma unroll
    for (int e = 0; e < 4; ++e) {
        const int cwi[4] = {0, 1, 2, 3};
        const int twi[4] = {1, 2, 3, 0};
        int mc = 1 << (3 - cwi[e]), mt = 1 << (3 - twi[e]);
#pragma unroll
        for (int k = 0; k < 16; ++k) {
            if ((k & mc) && !(k & mt)) {
                int k2 = k | mt;
                float tr = ar[k]; ar[k] = ar[k2]; ar[k2] = tr;
                float ti = ai[k]; ai[k] = ai[k2]; ai[k2] = ti;
            }
        }
    }
    float zz[4] = {0.f, 0.f, 0.f, 0.f};
#pragma unroll
    for (int k = 0; k < 16; ++k) {
        float p = ar[k] * ar[k] + ai[k] * ai[k];
#pragma unroll
        for (int w = 0; w < 4; ++w) zz[w] += ((k >> (3 - w)) & 1) ? -p : p;
    }
#pragma unroll
    for (int w = 0; w < 4; ++w) z[w] = zz[w];
}

__global__ void k_circ1(const float* __restrict__ pooled, const float* __restrict__ qp,
                        float* __restrict__ y1) {
    int tid = threadIdx.x;
    if (tid >= 48) return;
    int b = tid / 3, g = tid % 3;
    float z[4];
    run_circuit(pooled + b * 12 + g * 4, qp + g * 4, z);
#pragma unroll
    for (int w = 0; w < 4; ++w) y1[b * 12 + g * 4 + w] = z[w];
}

__global__ void k_circ2(const float* __restrict__ y1, const float* __restrict__ A,
                        const float* __restrict__ B, const float* __restrict__ qp,
                        float* __restrict__ y2) {
    int tid = threadIdx.x;
    if (tid >= 48) return;
    int b = tid / 3, g = tid % 3;
    float pin[4], z[4];
#pragma unroll
    for (int w = 0; w < 4; ++w) {
        int c = g * 4 + w;
        float v = y1[b * 12 + c];
        pin[w] = swishf(v * A[b * 128 + c] + B[b * 128 + c]);
    }
    run_circuit(pin, qp + g * 4, z);
#pragma unroll
    for (int w = 0; w < 4; ++w) y2[b * 12 + g * 4 + w] = z[w];
}

// ---------------- time MLP: t = swish(te) @ W + b ----------------
__global__ void k_time(const float* __restrict__ te, const float* __restrict__ W,
                       const float* __restrict__ tb, float* __restrict__ t) {
    int b = blockIdx.x, tid = threadIdx.x;
    __shared__ float se[512];
    for (int k = tid; k < 512; k += 256) {
        float z = te[b * 512 + k];
        se[k] = swishf(z);
    }
    __syncthreads();
    float acc = tb[tid];
    for (int k = 0; k < 512; ++k) acc += se[k] * W[k * 256 + tid];
    t[b * 256 + tid] = acc;
}

// ---------------- weight standardization -> packed bf16 B-fragment layout ----------------
// pack[(tap*4+ch)*8 + g][lane][j] = Wstd[tap][ic = ch*32 + (lane>>4)*8 + j][oc = g*16 + (lane&15)]
__global__ void k_wstd(const float* __restrict__ K, u16* __restrict__ kqp) {
    int o = blockIdx.x;
    int tid = threadIdx.x;
    __shared__ float rs[256], rss[256];
    __shared__ float mb[2];
    float s = 0.f, ss = 0.f;
    if (o < CC) {
        for (int idx = tid; idx < KTAPS; idx += 256) {
            float v = K[(size_t)idx * CC + o];
            s += v; ss += v * v;
        }
    }
    rs[tid] = s; rss[tid] = ss;
    __syncthreads();
    for (int st = 128; st > 0; st >>= 1) {
        if (tid < st) { rs[tid] += rs[tid + st]; rss[tid] += rss[tid + st]; }
        __syncthreads();
    }
    if (tid == 0) {
        float m = rs[0] * (1.f / KTAPS);
        float var = rss[0] * (1.f / KTAPS) - m * m;
        mb[0] = m;
        mb[1] = rsqrtf(var + 1e-5f);
    }
    __syncthreads();
    float m = mb[0], inv = mb[1];
    int g = o >> 4, ol = o & 15;
    for (int idx = tid; idx < 1152; idx += 256) {
        int tap = idx >> 7, r = idx & 127;
        int ch = r >> 5, kgv = (r >> 3) & 3, j = r & 7;
        int ic = ch * 32 + kgv * 8 + j;
        float v = 0.f;
        if (o < CC && ic < CC) v = (K[((size_t)tap * CC + ic) * CC + o] - m) * inv;
        kqp[(size_t)((tap * 4 + ch) * 8 + g) * 512 + (size_t)(kgv * 16 + ol) * 8 + j] = f2bf(v);
    }
}

// ---------------- MFMA implicit-GEMM conv: 64px x 128oc per block ----------------
__launch_bounds__(256)
__global__ void k_conv(const u16* __restrict__ act, const u16* __restrict__ kqp,
                       const float* __restrict__ bias, u16* __restrict__ outp) {
    __shared__ u16 As[3 * 66 * 128];   // [p][pp(0..65)][128 ic], XOR-swizzled 16B blocks
    const int h = blockIdx.x, b = blockIdx.y;
    const int tid = threadIdx.x, lane = tid & 63, wid = tid >> 6;
    const int wm = wid & 1, wn = wid >> 1;

    // zero halo columns pp=0,65 (always out-of-image since tile spans full width)
    for (int i = tid; i < 384; i += 256) {
        int grp = i >> 6, c2 = i & 63;
        int p = grp >> 1, pp = (grp & 1) ? 65 : 0;
        ((unsigned int*)As)[(p * 66 + pp) * 64 + c2] = 0u;
    }
    if (h == 0)  for (int i = tid; i < 4224; i += 256) ((unsigned int*)As)[i] = 0u;
    if (h == 63) for (int i = tid; i < 4224; i += 256) ((unsigned int*)As)[8448 + i] = 0u;

    // stage interior: rows h-1..h+1, 64 px each; linear LDS dest + inverse-swizzled source
    for (int idx = wid; idx < 48; idx += 4) {
        int p = idx >> 4, seg = idx & 15;
        int hi = h + p - 1;
        if (hi >= 0 && hi < 64) {
            int pp = 1 + seg * 4 + (lane >> 4);
            const u16* src = act + ((size_t)(b * 64 + hi) * 64 + (size_t)(pp - 1)) * 128
                           + ((((lane & 15) * 16) ^ ((pp & 7) * 16)) >> 1);
            u16* dst = &As[(p * 66 + 1 + seg * 4) * 128];
            __builtin_amdgcn_global_load_lds((const __attribute__((address_space(1))) void*)src,
                                             (__attribute__((address_space(3))) void*)dst, 16, 0, 0);
        }
    }
    __syncthreads();

    const int col = lane & 15, kg = lane >> 4;
    const int kg16 = kg * 16;
    int ppm[2], swz[2][3], rowb[2][3];
#pragma unroll
    for (int mf = 0; mf < 2; ++mf) {
        ppm[mf] = wm * 32 + mf * 16 + col;
#pragma unroll
        for (int q = 0; q < 3; ++q) {
            int pp = ppm[mf] + q;
            swz[mf][q] = (pp & 7) * 16;
            rowb[mf][q] = pp * 128;
        }
    }
    const u16* bptr = kqp + (size_t)(wn * 4) * 512 + (size_t)lane * 8;

    f32x4 acc[2][4];
#pragma unroll
    for (int mf = 0; mf < 2; ++mf)
#pragma unroll
        for (int nf = 0; nf < 4; ++nf) acc[mf][nf] = (f32x4){0.f, 0.f, 0.f, 0.f};

    short8 breg[3][4];
#pragma unroll
    for (int s = 0; s < 2; ++s)
#pragma unroll
        for (int nf = 0; nf < 4; ++nf)
            breg[s][nf] = *(const short8*)(bptr + (size_t)s * 4096 + nf * 512);

#pragma unroll
    for (int step = 0; step < 36; ++step) {
        const int tap = step >> 2, ch = step & 3;
        const int p = tap / 3, q = tap % 3;
        const int cb = step % 3, nb = (step + 2) % 3;
        if (step + 2 < 36) {
#pragma unroll
            for (int nf = 0; nf < 4; ++nf)
                breg[nb][nf] = *(const short8*)(bptr + (size_t)(step + 2) * 4096 + nf * 512);
        }
        short8 a[2];
#pragma unroll
        for (int mf = 0; mf < 2; ++mf) {
            int off = ((ch * 64 + kg16) ^ swz[mf][q]) >> 1;
            a[mf] = *(const short8*)&As[p * 8448 + rowb[mf][q] + off];
        }
#pragma unroll
        for (int mf = 0; mf < 2; ++mf)
#pragma unroll
            for (int nf = 0; nf < 4; ++nf)
                acc[mf][nf] = __builtin_amdgcn_mfma_f32_16x16x32_bf16(a[mf], breg[cb][nf],
                                                                     acc[mf][nf], 0, 0, 0);
    }

    float bv[4];
#pragma unroll
    for (int nf = 0; nf < 4; ++nf) {
        int oc = wn * 64 + nf * 16 + col;
        bv[nf] = (oc < CC) ? bias[oc] : 0.f;
    }
    size_t obase = ((size_t)b * NPX + (size_t)h * 64) * 128;
#pragma unroll
    for (int mf = 0; mf < 2; ++mf) {
#pragma unroll
        for (int reg = 0; reg < 4; ++reg) {
            int px = wm * 32 + mf * 16 + kg * 4 + reg;
#pragma unroll
            for (int nf = 0; nf < 4; ++nf) {
                int oc = wn * 64 + nf * 16 + col;
                outp[obase + (size_t)px * 128 + oc] = f2bf(acc[mf][nf][reg] + bv[nf]);
            }
        }
    }
}

// ---------------- per (b, channel) sum & sumsq over px ----------------
__global__ void k_csum(const u16* __restrict__ co, float* __restrict__ csum) {
    int bc = blockIdx.x;            // 64 = 16 b * 4 channel-groups
    int b = bc >> 2, cg = bc & 3;
    int tid = threadIdx.x;
    int s = tid & 3, pxt = tid >> 2;
    int ch8 = cg * 32 + s * 8;
    const u16* base = co + (size_t)b * NPX * 128 + ch8;
    float sm[8], sq[8];
#pragma unroll
    for (int j = 0; j < 8; ++j) { sm[j] = 0.f; sq[j] = 0.f; }
    for (int i = 0; i < 64; ++i) {
        int px = pxt + i * 64;
        short8 v = *(const short8*)(base + (size_t)px * 128);
#pragma unroll
        for (int j = 0; j < 8; ++j) { float f = bf2f((u16)v[j]); sm[j] += f; sq[j] += f * f; }
    }
    __shared__ float red[256][16];
    int row = s * 64 + pxt;
#pragma unroll
    for (int j = 0; j < 8; ++j) { red[row][j] = sm[j]; red[row][8 + j] = sq[j]; }
    __syncthreads();
    if (tid < 64) {
        int s2 = tid >> 4, rem = tid & 15, j = rem >> 1, mth = rem & 1;
        int k = (mth == 0) ? j : 8 + j;
        float acc = 0.f;
        for (int pt = 0; pt < 64; ++pt) acc += red[s2 * 64 + pt][k];
        csum[(size_t)(b * 128 + cg * 32 + s2 * 8 + j) * 2 + mth] = acc;
    }
}

// ---------------- combine channel sums into group stats (+ quantum closed form) ----------------
__global__ void k_gstat(const float* __restrict__ csum, const float* __restrict__ y,
                        float* __restrict__ stats) {
    int t = threadIdx.x;
    if (t >= 128) return;
    int b = t >> 3, g = t & 7;
    float S = 0.f, SS = 0.f;
#pragma unroll
    for (int e = 0; e < 16; ++e) {
        int orig = g * 16 + e;
        if (orig >= 12) {
            int cc = orig - 12;
            S += csum[(b * 128 + cc) * 2];
            SS += csum[(b * 128 + cc) * 2 + 1];
        }
    }
    if (g == 0) {
#pragma unroll
        for (int c = 0; c < 12; ++c) {
            float v = y[b * 12 + c];
            S += 4096.f * v;
            SS += 4096.f * v * v;
        }
    }
    float mu = S * (1.f / 65536.f);
    float var = SS * (1.f / 65536.f) - mu * mu;
    stats[t * 2] = mu;
    stats[t * 2 + 1] = rsqrtf(var + 1e-6f);
}

// ---------------- per-(b,c) affine coefficients ----------------
__global__ void k_coef0(const float* __restrict__ stats, const float* __restrict__ gs,
                        const float* __restrict__ gb, const float* __restrict__ t,
                        float* __restrict__ A, float* __restrict__ B) {
    int idx = blockIdx.x * 256 + threadIdx.x;
    if (idx >= 16 * 128) return;
    int b = idx >> 7, c = idx & 127, g = c >> 4;
    float mu = stats[(b * 8 + g) * 2], isd = stats[(b * 8 + g) * 2 + 1];
    float sc = t[b * 256 + c], sh = t[b * 256 + 128 + c];
    float a = isd * gs[c];
    float bb = gb[c] - mu * a;
    A[idx] = a * (1.f + sc);
    B[idx] = bb * (1.f + sc) + sh;
}

__global__ void k_coef1(const float* __restrict__ stats, const float* __restrict__ gs,
                        const float* __restrict__ gb, const float* __restrict__ y2,
                        float* __restrict__ A2, float* __restrict__ B2,
                        float* __restrict__ oq) {
    int idx = blockIdx.x * 256 + threadIdx.x;
    if (idx >= 16 * 128) return;
    int b = idx >> 7, c = idx & 127, g = c >> 4;
    float mu = stats[(b * 8 + g) * 2], isd = stats[(b * 8 + g) * 2 + 1];
    float a = isd * gs[c];
    float bb = gb[c] - mu * a;
    A2[idx] = a;
    B2[idx] = bb;
    if (c < 12) oq[b * 12 + c] = swishf(y2[b * 12 + c] * a + bb);
}

// ---------------- h_act = swish(A*hc + B) -> bf16 act buffer ----------------
__global__ void k_hact(const u16* __restrict__ co, const float* __restrict__ A,
                       const float* __restrict__ Bc, u16* __restrict__ act) {
    int gid = blockIdx.x * 256 + threadIdx.x;
    if (gid >= BATCH * NPX * 4) return;
    int px = gid >> 2, part = gid & 3;
    int b = px >> 12;
    const u16* hp = co + (size_t)px * 128 + part * 32;
    u16* ap = act + (size_t)px * 128 + part * 32;
#pragma unroll
    for (int j = 0; j < 4; ++j) {
        short8 v = *(const short8*)(hp + j * 8);
        u16 outv[8];
#pragma unroll
        for (int e = 0; e < 8; ++e) {
            int cc = part * 32 + j * 8 + e;
            if (cc < CC) {
                int idx = b * 128 + cc + 12;
                float f = bf2f((u16)v[e]);
                outv[e] = f2bf(swishf(f * A[idx] + Bc[idx]));
            } else outv[e] = 0;
        }
        *(short8*)(ap + j * 8) = *(const short8*)outv;
    }
}

// ---------------- out = x + swish(A2*v + B2) ----------------
__global__ void k_final(const float* __restrict__ x, const u16* __restrict__ co,
                        const float* __restrict__ A2, const float* __restrict__ B2,
                        const float* __restrict__ oq, float* __restrict__ outp) {
    int idx = blockIdx.x * 256 + threadIdx.x;
    const int n = BATCH * NPX * 32;
    if (idx >= n) return;
    int px = idx >> 5, c4 = idx & 31;
    int b = px >> 12, c = c4 * 4;
    float4 xv = *(const float4*)(x + (size_t)px * CDIM + c);
    float4 r;
    if (c4 < 3) {
        const float* q = oq + b * 12 + c;
        r.x = xv.x + q[0]; r.y = xv.y + q[1]; r.z = xv.z + q[2]; r.w = xv.w + q[3];
    } else {
        int cc = c - 12;
        const u16* hp = co + (size_t)px * 128 + cc;
        float4 a = *(const float4*)(A2 + b * 128 + c);
        float4 bb = *(const float4*)(B2 + b * 128 + c);
        r.x = xv.x + swishf(bf2f(hp[0]) * a.x + bb.x);
        r.y = xv.y + swishf(bf2f(hp[1]) * a.y + bb.y);
        r.z = xv.z + swishf(bf2f(hp[2]) * a.z + bb.z);
        r.w = xv.w + swishf(bf2f(hp[3]) * a.w + bb.w);
    }
    *(float4*)(outp + (size_t)px * CDIM + c) = r;
}

extern "C" void kernel_launch(void* const* d_in, const int* in_sizes, int n_in,
                              void* d_out, int out_size, void* d_ws, size_t ws_size,
                              hipStream_t stream) {
    const float* x        = (const float*)d_in[0];
    const float* time_emb = (const float*)d_in[1];
    const float* qparams  = (const float*)d_in[2];
    const float* c0k      = (const float*)d_in[3];
    const float* c0b      = (const float*)d_in[4];
    const float* c1k      = (const float*)d_in[5];
    const float* c1b      = (const float*)d_in[6];
    const float* g0s      = (const float*)d_in[7];
    const float* g0b      = (const float*)d_in[8];
    const float* g1s      = (const float*)d_in[9];
    const float* g1b      = (const float*)d_in[10];
    const float* tw       = (const float*)d_in[11];
    const float* tb       = (const float*)d_in[12];
    float* outp = (float*)d_out;
    float* ws = (float*)d_ws;

    size_t o = 0;
    auto alloc = [&](size_t n) { size_t r = o; o += (n + 15) & ~(size_t)15; return r; };
    float* pooled = ws + alloc(192);
    float* y1     = ws + alloc(192);
    float* y2     = ws + alloc(192);
    float* t      = ws + alloc(4096);
    float* st0    = ws + alloc(256);
    float* st1    = ws + alloc(256);
    float* A      = ws + alloc(2048);
    float* Bc     = ws + alloc(2048);
    float* A2     = ws + alloc(2048);
    float* B2     = ws + alloc(2048);
    float* oq     = ws + alloc(192);
    float* csum   = ws + alloc(4096);
    u16* kqp0     = (u16*)(ws + alloc(73728));   // 9*4*8*64*8 bf16
    u16* kqp1     = (u16*)(ws + alloc(73728));
    u16* convout  = (u16*)(ws + alloc(4194304)); // [16][4096][128] bf16
    u16* actbuf   = (u16*)d_out;                 // bf16 activations live in d_out until k_final

    k_prep<<<1024, 256, 0, stream>>>(x, actbuf);
    k_pool<<<16, 256, 0, stream>>>(x, pooled);
    k_circ1<<<1, 64, 0, stream>>>(pooled, qparams, y1);
    k_time<<<16, 256, 0, stream>>>(time_emb, tw, tb, t);
    k_wstd<<<128, 256, 0, stream>>>(c0k, kqp0);
    k_wstd<<<128, 256, 0, stream>>>(c1k, kqp1);

    dim3 cgrid(64, 16);
    k_conv<<<cgrid, 256, 0, stream>>>(actbuf, kqp0, c0b, convout);
    k_csum<<<64, 256, 0, stream>>>(convout, csum);
    k_gstat<<<1, 128, 0, stream>>>(csum, y1, st0);
    k_coef0<<<8, 256, 0, stream>>>(st0, g0s, g0b, t, A, Bc);
    k_hact<<<1024, 256, 0, stream>>>(convout, A, Bc, actbuf);
    k_circ2<<<1, 64, 0, stream>>>(y1, A, Bc, qparams, y2);

    k_conv<<<cgrid, 256, 0, stream>>>(actbuf, kqp1, c1b, convout);
    k_csum<<<64, 256, 0, stream>>>(convout, csum);
    k_gstat<<<1, 128, 0, stream>>>(csum, y2, st1);
    k_coef1<<<8, 256, 0, stream>>>(st1, g1s, g1b, y2, A2, B2, oq);
    k_final<<<8192, 256, 0, stream>>>(x, convout, A2, B2, oq, outp);
}